// Round 9
// baseline (552.263 us; speedup 1.0000x reference)
//
#include <hip/hip_runtime.h>
#include <cstdint>
#include <cstddef>

#define T_DIM 256
#define H_DIM 4096
#define I_DIM 14336
// GROUP_SIZE = 64 == BK: one (scale,zero) per row per K-tile.

typedef __attribute__((ext_vector_type(8))) short s8v;   // 8 bf16
typedef __attribute__((ext_vector_type(4))) float f4v;   // MFMA C/D frag

// Workspace layout (two base modes; PRT first so tiers keep fixed offsets)
static constexpr size_t PRT_OFF   = 0;                  // 16 MB: 4 fp32 partials
static constexpr size_t XS_OFF    = 16777216;           // 2 MB: x bf16 frag-major
static constexpr size_t ACT_OFF   = 18874368;           // 7.34 MB: act bf16 frag-major
static constexpr size_t P1_OFF    = 26214400;           // 29.36 MB packed w1
static constexpr size_t P3_OFF    = 55574528;           // packed w3
static constexpr size_t P2_OFF    = 84934656;           // packed w2
static constexpr size_t WS_PACKED = 114294784;          // full tier
static constexpr size_t WS_PART   = 26214400;           // partials tier (unpacked)

__device__ __forceinline__ unsigned short f2bf(float f) {
    unsigned u = __builtin_bit_cast(unsigned, f);
    u += 0x7fffu + ((u >> 16) & 1u);
    return (unsigned short)(u >> 16);
}

__device__ __forceinline__ void g2lds16(const void* g, void* l) {
    __builtin_amdgcn_global_load_lds(
        (const __attribute__((address_space(1))) unsigned int*)g,
        (__attribute__((address_space(3))) unsigned int*)l,
        16, 0, 0);
}

// dequant 8 nibbles of one dword -> 8 bf16: w = q*s + ns, ns = -z*s
__device__ __forceinline__ s8v dqw(unsigned dw, float s, float ns) {
    float f0 = fmaf((float)(dw & 15u), s, ns);
    float f1 = fmaf((float)((dw >> 4) & 15u), s, ns);
    float f2 = fmaf((float)((dw >> 8) & 15u), s, ns);
    float f3 = fmaf((float)((dw >> 12) & 15u), s, ns);
    float f4 = fmaf((float)((dw >> 16) & 15u), s, ns);
    float f5 = fmaf((float)((dw >> 20) & 15u), s, ns);
    float f6 = fmaf((float)((dw >> 24) & 15u), s, ns);
    float f7 = fmaf((float)(dw >> 28), s, ns);
    unsigned r0, r1, r2, r3;
    asm("v_cvt_pk_bf16_f32 %0, %1, %2" : "=v"(r0) : "v"(f0), "v"(f1));
    asm("v_cvt_pk_bf16_f32 %0, %1, %2" : "=v"(r1) : "v"(f2), "v"(f3));
    asm("v_cvt_pk_bf16_f32 %0, %1, %2" : "=v"(r2) : "v"(f4), "v"(f5));
    asm("v_cvt_pk_bf16_f32 %0, %1, %2" : "=v"(r3) : "v"(f6), "v"(f7));
    union { unsigned u[4]; s8v v; } o;
    o.u[0] = r0; o.u[1] = r1; o.u[2] = r2; o.u[3] = r3;
    return o.v;
}

// dequant 8 raw int32 -> 8 bf16 (unpacked fallback; verified R6)
__device__ __forceinline__ s8v dq8f(const int4 qa, const int4 qb, float s, float ns) {
    float f0 = fmaf((float)qa.x, s, ns), f1 = fmaf((float)qa.y, s, ns);
    float f2 = fmaf((float)qa.z, s, ns), f3 = fmaf((float)qa.w, s, ns);
    float f4 = fmaf((float)qb.x, s, ns), f5 = fmaf((float)qb.y, s, ns);
    float f6 = fmaf((float)qb.z, s, ns), f7 = fmaf((float)qb.w, s, ns);
    unsigned r0, r1, r2, r3;
    asm("v_cvt_pk_bf16_f32 %0, %1, %2" : "=v"(r0) : "v"(f0), "v"(f1));
    asm("v_cvt_pk_bf16_f32 %0, %1, %2" : "=v"(r1) : "v"(f2), "v"(f3));
    asm("v_cvt_pk_bf16_f32 %0, %1, %2" : "=v"(r2) : "v"(f4), "v"(f5));
    asm("v_cvt_pk_bf16_f32 %0, %1, %2" : "=v"(r3) : "v"(f6), "v"(f7));
    union { unsigned u[4]; s8v v; } o;
    o.u[0] = r0; o.u[1] = r1; o.u[2] = r2; o.u[3] = r3;
    return o.v;
}

// ---------------------------------------------------------------------------
// k_prep: x fp32 [256,4096] -> bf16 A-fragment-major (verified R5 layout):
// frag f = (k>>5)*16 + (m>>4); lane = (m&15) + 16*((k>>3)&3); byte f*1024 +
// lane*16 + (k&7)*2.
// ---------------------------------------------------------------------------
__global__ __launch_bounds__(256) void k_prep(const float* __restrict__ x,
                                              unsigned short* __restrict__ xs) {
    int t = blockIdx.x * 256 + threadIdx.x;
    int l = t & 63, f = t >> 6;
    int msub = f & 15, ksub = f >> 4;
    int m = msub * 16 + (l & 15);
    int k = ksub * 32 + (l >> 4) * 8;
    const float* xp = x + (size_t)m * H_DIM + k;
    float4 a = *(const float4*)xp;
    float4 b = *(const float4*)(xp + 4);
    union { unsigned short u[8]; s8v v; } r;
    r.u[0] = f2bf(a.x); r.u[1] = f2bf(a.y); r.u[2] = f2bf(a.z); r.u[3] = f2bf(a.w);
    r.u[4] = f2bf(b.x); r.u[5] = f2bf(b.y); r.u[6] = f2bf(b.z); r.u[7] = f2bf(b.w);
    *((s8v*)xs + t) = r.v;
}

// ---------------------------------------------------------------------------
// w_pack: int32 weights [R][K] (values 0..15) -> 4-bit packed, tile-contiguous
// fragment order. dword P(nb,kt,grp,ks,lane) = nb*64*K8 + ((kt*4+grp)*2+ks)*64
// + lane holds row nb*64+grp*16+(lane&15), octet kt*8+ks*4+(lane>>4)
// (8 consecutive k). Reads are fully sequential (copy-pattern) 32 B/thread.
// ---------------------------------------------------------------------------
__global__ __launch_bounds__(256) void w_pack(const int* __restrict__ wq,
                                              unsigned* __restrict__ p,
                                              int K8, int bpr) {
    int bx  = blockIdx.x;
    int row = bx / bpr;
    int oct = (bx - row * bpr) * 256 + threadIdx.x;    // 0..K8-1
    const int4* src = (const int4*)(wq + (size_t)row * (K8 * 8) + oct * 8);
    int4 a = src[0], b = src[1];
    unsigned dw = (unsigned)(a.x & 15) | ((unsigned)(a.y & 15) << 4)
                | ((unsigned)(a.z & 15) << 8) | ((unsigned)(a.w & 15) << 12)
                | ((unsigned)(b.x & 15) << 16) | ((unsigned)(b.y & 15) << 20)
                | ((unsigned)(b.z & 15) << 24) | ((unsigned)(b.w & 15) << 28);
    int nb = row >> 6, rl = row & 63, grp = rl >> 4;
    int kt = oct >> 3, ks = (oct >> 2) & 1, lane = (rl & 15) + ((oct & 3) << 4);
    p[(size_t)nb * (64 * (size_t)K8) + ((kt * 4 + grp) * 2 + ks) * 64 + lane] = dw;
}

// ---------------------------------------------------------------------------
// k_gemm1: fused gate/up GEMM. BM=256, BN=64, BK=64, grid 224, 8 waves (4Mx2N).
// One plain __syncthreads per tile: {stage x(t+1) + wload(t+1) -> compute(t)
// -> sync}. Weights direct-to-reg (packed: 1 dword = 1 B-frag, coalesced).
// ---------------------------------------------------------------------------
struct Sc1 { float s1[2], z1[2], s3[2], z3[2]; };

template<bool PACKED>
__global__ __launch_bounds__(512) void k_gemm1(
    const int* __restrict__ w1q, const float* __restrict__ w1s, const float* __restrict__ w1z,
    const int* __restrict__ w3q, const float* __restrict__ w3s, const float* __restrict__ w3z,
    const unsigned* __restrict__ p1, const unsigned* __restrict__ p3,
    const unsigned char* __restrict__ xs, unsigned char* __restrict__ act)
{
    __shared__ unsigned char xbuf[2][32768];
    const int tid = threadIdx.x, wid = tid >> 6, l = tid & 63;
    const int lr = l & 15, lk = l >> 4;
    const int wr = wid >> 1, wc = wid & 1;
    const int nb = blockIdx.x, n0 = nb * 64;

    const unsigned char* xsrc0 = xs + (size_t)(wid * 4) * 1024 + (size_t)l * 16;
    const unsigned* p1b = p1 + (size_t)nb * 32768 + l;
    const unsigned* p3b = p3 + (size_t)nb * 32768 + l;
    const int row0 = n0 + wc * 32 + lr;        // nf=0 weight row for this lane
    const int row1 = row0 + 16;                // nf=1

    f4v accg[4][2], accu[4][2];
    const f4v fz = {0.f, 0.f, 0.f, 0.f};
    #pragma unroll
    for (int i = 0; i < 4; ++i)
        #pragma unroll
        for (int j = 0; j < 2; ++j) { accg[i][j] = fz; accu[i][j] = fz; }

    unsigned Dp1[2][4], Dp3[2][4];             // packed: [slot][nf*2+ks]
    int4 Qa1[2][4], Qb1[2][4], Qa3[2][4], Qb3[2][4];   // unpacked
    Sc1 S[2];

    auto stage = [&](int t) {
        unsigned char* dst = xbuf[t & 1] + (size_t)(wid * 4) * 1024;  // wave-uniform
        const unsigned char* src = xsrc0 + (size_t)t * 32768;
        #pragma unroll
        for (int j = 0; j < 4; ++j)
            g2lds16(src + j * 1024, dst + j * 1024);
    };
    auto wload = [&](int kt, int slot) {
        #pragma unroll
        for (int nf = 0; nf < 2; ++nf) {
            const int row = nf ? row1 : row0;
            S[slot].s1[nf] = w1s[(size_t)row * 64 + kt];
            S[slot].z1[nf] = w1z[(size_t)row * 64 + kt];
            S[slot].s3[nf] = w3s[(size_t)row * 64 + kt];
            S[slot].z3[nf] = w3z[(size_t)row * 64 + kt];
            #pragma unroll
            for (int ks = 0; ks < 2; ++ks) {
                if constexpr (PACKED) {
                    const int off = ((kt * 4 + wc * 2 + nf) * 2 + ks) * 64;
                    Dp1[slot][nf * 2 + ks] = p1b[off];
                    Dp3[slot][nf * 2 + ks] = p3b[off];
                } else {
                    const int4* q1 = (const int4*)(w1q + (size_t)row * H_DIM + kt * 64 + ks * 32 + lk * 8);
                    const int4* q3 = (const int4*)(w3q + (size_t)row * H_DIM + kt * 64 + ks * 32 + lk * 8);
                    Qa1[slot][nf * 2 + ks] = q1[0]; Qb1[slot][nf * 2 + ks] = q1[1];
                    Qa3[slot][nf * 2 + ks] = q3[0]; Qb3[slot][nf * 2 + ks] = q3[1];
                }
            }
        }
    };
    auto compute = [&](int t, int slot) {
        const unsigned char* xb = xbuf[t & 1];
        #pragma unroll
        for (int ks = 0; ks < 2; ++ks) {
            s8v a[4];
            #pragma unroll
            for (int mf = 0; mf < 4; ++mf)
                a[mf] = *(const s8v*)(xb + (ks * 16 + wr * 4 + mf) * 1024 + l * 16);
            #pragma unroll
            for (int nf = 0; nf < 2; ++nf) {
                const float ss1 = S[slot].s1[nf], nz1 = -S[slot].z1[nf] * ss1;
                const float ss3 = S[slot].s3[nf], nz3 = -S[slot].z3[nf] * ss3;
                s8v B1, B3;
                if constexpr (PACKED) {
                    B1 = dqw(Dp1[slot][nf * 2 + ks], ss1, nz1);
                    B3 = dqw(Dp3[slot][nf * 2 + ks], ss3, nz3);
                } else {
                    B1 = dq8f(Qa1[slot][nf * 2 + ks], Qb1[slot][nf * 2 + ks], ss1, nz1);
                    B3 = dq8f(Qa3[slot][nf * 2 + ks], Qb3[slot][nf * 2 + ks], ss3, nz3);
                }
                #pragma unroll
                for (int mf = 0; mf < 4; ++mf) {
                    accg[mf][nf] = __builtin_amdgcn_mfma_f32_16x16x32_bf16(a[mf], B1, accg[mf][nf], 0, 0, 0);
                    accu[mf][nf] = __builtin_amdgcn_mfma_f32_16x16x32_bf16(a[mf], B3, accu[mf][nf], 0, 0, 0);
                }
            }
        }
    };

    stage(0); wload(0, 0);
    __syncthreads();
    for (int i = 0; i < 32; ++i) {
        const int t = i * 2;
        if (t + 1 < 64) { stage(t + 1); wload(t + 1, 1); }   // in flight under compute(t)
        compute(t, 0);
        __syncthreads();                                      // drains t+1 loads
        if (t + 2 < 64) { stage(t + 2); wload(t + 2, 0); }
        compute(t + 1, 1);
        __syncthreads();
    }

    // epilogue: act = silu(g)*u, A-frag-major for gemm2 (K-dim = I)
    unsigned char* ab = act + (size_t)nb * 32768;
    #pragma unroll
    for (int mf = 0; mf < 4; ++mf)
        #pragma unroll
        for (int nf = 0; nf < 2; ++nf)
            #pragma unroll
            for (int r = 0; r < 4; ++r) {
                float g = accg[mf][nf][r], u = accu[mf][nf][r];
                float sg = g / (1.0f + __expf(-g));
                const int F     = wc * 16 + wr * 4 + mf;
                const int lane2 = (lk * 4 + r) + 16 * (nf * 2 + (lr >> 3));
                *(unsigned short*)(ab + F * 1024 + lane2 * 16 + (lr & 7) * 2) = f2bf(sg * u);
            }
}

// ---------------------------------------------------------------------------
// k_gemm2: out_partial[kc] = act[:, chunk] @ w2[:, chunk]^T. BM=256, BN=64,
// 4 kc x 56 tiles, grid 256 (kc per XCD-pair -> act slice L2-resident).
// Same one-barrier structure.
// ---------------------------------------------------------------------------
struct Sc2 { float s[2], z[2]; };

template<bool PACKED, bool ATOMIC>
__global__ __launch_bounds__(512) void k_gemm2(
    const int* __restrict__ w2q, const float* __restrict__ w2s, const float* __restrict__ w2z,
    const unsigned* __restrict__ p2,
    const unsigned char* __restrict__ act, float* __restrict__ outp)
{
    __shared__ unsigned char xbuf[2][32768];
    const int tid = threadIdx.x, wid = tid >> 6, l = tid & 63;
    const int lr = l & 15, lk = l >> 4;
    const int wr = wid >> 1, wc = wid & 1;
    const int bx = blockIdx.x;
    const int kc = (bx & 7) >> 1;
    const int nb = (bx >> 3) * 2 + (bx & 1);
    const int n0 = nb * 64;
    const int T0 = kc * 56;

    const unsigned char* asrc0 = act + (size_t)(wid * 4) * 1024 + (size_t)l * 16;
    const unsigned* p2b = p2 + (size_t)nb * 114688 + l;
    const int row0 = n0 + wc * 32 + lr;
    const int row1 = row0 + 16;

    f4v acc[4][2];
    const f4v fz = {0.f, 0.f, 0.f, 0.f};
    #pragma unroll
    for (int i = 0; i < 4; ++i) { acc[i][0] = fz; acc[i][1] = fz; }

    unsigned Dp[2][4];
    int4 Qa[2][4], Qb[2][4];
    Sc2 S[2];

    auto stage = [&](int t) {
        unsigned char* dst = xbuf[t & 1] + (size_t)(wid * 4) * 1024;
        const unsigned char* src = asrc0 + (size_t)(T0 + t) * 32768;
        #pragma unroll
        for (int j = 0; j < 4; ++j)
            g2lds16(src + j * 1024, dst + j * 1024);
    };
    auto wload = [&](int t, int slot) {
        const int kt = T0 + t;
        #pragma unroll
        for (int nf = 0; nf < 2; ++nf) {
            const int row = nf ? row1 : row0;
            S[slot].s[nf] = w2s[(size_t)row * 224 + kt];
            S[slot].z[nf] = w2z[(size_t)row * 224 + kt];
            #pragma unroll
            for (int ks = 0; ks < 2; ++ks) {
                if constexpr (PACKED) {
                    Dp[slot][nf * 2 + ks] = p2b[((kt * 4 + wc * 2 + nf) * 2 + ks) * 64];
                } else {
                    const int4* q = (const int4*)(w2q + (size_t)row * I_DIM + kt * 64 + ks * 32 + lk * 8);
                    Qa[slot][nf * 2 + ks] = q[0]; Qb[slot][nf * 2 + ks] = q[1];
                }
            }
        }
    };
    auto compute = [&](int t, int slot) {
        const unsigned char* xb = xbuf[t & 1];
        #pragma unroll
        for (int ks = 0; ks < 2; ++ks) {
            s8v a[4];
            #pragma unroll
            for (int mf = 0; mf < 4; ++mf)
                a[mf] = *(const s8v*)(xb + (ks * 16 + wr * 4 + mf) * 1024 + l * 16);
            #pragma unroll
            for (int nf = 0; nf < 2; ++nf) {
                const float ss = S[slot].s[nf], nz = -S[slot].z[nf] * ss;
                s8v B = PACKED ? dqw(Dp[slot][nf * 2 + ks], ss, nz)
                               : dq8f(Qa[slot][nf * 2 + ks], Qb[slot][nf * 2 + ks], ss, nz);
                #pragma unroll
                for (int mf = 0; mf < 4; ++mf)
                    acc[mf][nf] = __builtin_amdgcn_mfma_f32_16x16x32_bf16(a[mf], B, acc[mf][nf], 0, 0, 0);
            }
        }
    };

    stage(0); wload(0, 0);
    __syncthreads();
    for (int i = 0; i < 28; ++i) {
        const int t = i * 2;
        if (t + 1 < 56) { stage(t + 1); wload(t + 1, 1); }
        compute(t, 0);
        __syncthreads();
        if (t + 2 < 56) { stage(t + 2); wload(t + 2, 0); }
        compute(t + 1, 1);
        __syncthreads();
    }

    float* pout = outp + (ATOMIC ? 0 : (size_t)kc * ((size_t)T_DIM * H_DIM));
    #pragma unroll
    for (int mf = 0; mf < 4; ++mf)
        #pragma unroll
        for (int nf = 0; nf < 2; ++nf)
            #pragma unroll
            for (int r = 0; r < 4; ++r) {
                const int M = wr * 64 + mf * 16 + lk * 4 + r;
                const int N = n0 + wc * 32 + nf * 16 + lr;
                if (ATOMIC) atomicAdd(&outp[(size_t)M * H_DIM + N], acc[mf][nf][r]);
                else        pout[(size_t)M * H_DIM + N] = acc[mf][nf][r];
            }
}

__global__ __launch_bounds__(256) void k_reduce(const f4v* __restrict__ p,
                                                f4v* __restrict__ o) {
    int i = blockIdx.x * 256 + threadIdx.x;   // 262144 f4 groups
    f4v s = p[i];
    #pragma unroll
    for (int c = 1; c < 4; ++c) s += p[(size_t)c * 262144 + i];
    o[i] = s;
}

__global__ __launch_bounds__(256) void k_zero(f4v* __restrict__ o) {
    o[blockIdx.x * 256 + threadIdx.x] = (f4v){0.f, 0.f, 0.f, 0.f};
}

extern "C" void kernel_launch(void* const* d_in, const int* in_sizes, int n_in,
                              void* d_out, int out_size, void* d_ws, size_t ws_size,
                              hipStream_t stream) {
    const float* x   = (const float*)d_in[0];
    const int*   w1q = (const int*)  d_in[1];
    const float* w1s = (const float*)d_in[2];
    const float* w1z = (const float*)d_in[3];
    const int*   w3q = (const int*)  d_in[4];
    const float* w3s = (const float*)d_in[5];
    const float* w3z = (const float*)d_in[6];
    const int*   w2q = (const int*)  d_in[7];
    const float* w2s = (const float*)d_in[8];
    const float* w2z = (const float*)d_in[9];
    float* outp = (float*)d_out;

    const bool big    = (ws_size >= WS_PART);      // partials + big layout
    const bool packed = (ws_size >= WS_PACKED);

    unsigned short* xs  = (unsigned short*)((char*)d_ws + (big ? XS_OFF : 0));
    unsigned char*  act = (unsigned char*)d_ws + (big ? ACT_OFF : 2097152);
    float*    prt = (float*)d_ws;                         // valid iff big
    unsigned* p1  = (unsigned*)((char*)d_ws + P1_OFF);    // valid iff packed
    unsigned* p3  = (unsigned*)((char*)d_ws + P3_OFF);
    unsigned* p2  = (unsigned*)((char*)d_ws + P2_OFF);

    k_prep<<<512, 256, 0, stream>>>(x, xs);
    if (packed) {
        w_pack<<<28672, 256, 0, stream>>>(w1q, p1, 512, 2);
        w_pack<<<28672, 256, 0, stream>>>(w3q, p3, 512, 2);
        w_pack<<<28672, 256, 0, stream>>>(w2q, p2, 1792, 7);
        k_gemm1<true><<<224, 512, 0, stream>>>(w1q, w1s, w1z, w3q, w3s, w3z,
                                               p1, p3, (const unsigned char*)xs, act);
        k_gemm2<true, false><<<256, 512, 0, stream>>>(w2q, w2s, w2z, p2, act, prt);
        k_reduce<<<1024, 256, 0, stream>>>((const f4v*)prt, (f4v*)outp);
    } else {
        k_gemm1<false><<<224, 512, 0, stream>>>(w1q, w1s, w1z, w3q, w3s, w3z,
                                                p1, p3, (const unsigned char*)xs, act);
        if (big) {
            k_gemm2<false, false><<<256, 512, 0, stream>>>(w2q, w2s, w2z, p2, act, prt);
            k_reduce<<<1024, 256, 0, stream>>>((const f4v*)prt, (f4v*)outp);
        } else {
            k_zero<<<1024, 256, 0, stream>>>((f4v*)outp);
            k_gemm2<false, true><<<256, 512, 0, stream>>>(w2q, w2s, w2z, p2, act, outp);
        }
    }
}